// Round 3
// baseline (63.155 us; speedup 1.0000x reference)
//
#include <hip/hip_runtime.h>

// Problem constants (from reference): B=32, H=384, W=384, C=2
static constexpr int B_ = 32;
static constexpr int N_ = 384 * 384 * 2;          // 294912 elements per sample
static constexpr int CHUNKS = 64;                 // blocks per sample
static constexpr int EPB = N_ / CHUNKS;           // 4608 elements per block
static constexpr int TPB = 256;                   // 4 waves -> 8 blocks/CU (wave-limit)
static constexpr int NBINS = 2048;                // float bits >> 20: 8 exp + 3 mantissa
static constexpr int SHIFT = 20;
static constexpr int NEG_POS_RATIO = 3;
static constexpr int NCHUNKS_TOTAL = B_ * CHUNKS; // 2048 blocks, exactly 8/CU on 256 CUs

// ---------------------------------------------------------------------------
// Kernel 1: per-CHUNK histogram (count + sum) of neg values, plain stores
// (no atomics, no pre-zeroing); per-chunk pos/mse partials.
// ---------------------------------------------------------------------------
__global__ __launch_bounds__(TPB, 8) void k_hist(const float* __restrict__ y,
                                                 const float* __restrict__ o,
                                                 const float* __restrict__ w,
                                                 unsigned int* __restrict__ hcnt_part,
                                                 float* __restrict__ hsum_part,
                                                 double* __restrict__ pos_part,
                                                 double* __restrict__ mse_part) {
    __shared__ unsigned int lcnt[NBINS];
    __shared__ float lsum[NBINS];
    __shared__ double red[2 * (TPB / 64)];
    const int s = blockIdx.y;
    const int c = blockIdx.x;
    const int g = s * CHUNKS + c;                 // global chunk id
    const int t = threadIdx.x;
    for (int i = t; i < NBINS; i += TPB) { lcnt[i] = 0u; lsum[i] = 0.0f; }
    __syncthreads();

    const size_t base = (size_t)s * N_ + (size_t)c * EPB;
    double msed = 0.0, posd = 0.0;

#define PROC(yy, oo, ww)                                                        \
    {                                                                           \
        float d_ = (oo) - (yy);                                                 \
        float m_ = d_ * d_;                                                     \
        msed += (double)m_;                                                     \
        if ((ww) > 0.0f) {                                                      \
            posd += (double)(ww) * (double)m_;                                  \
        } else if ((oo) > 0.0f && m_ > 0.0f) {                                  \
            unsigned int b_ = __float_as_uint(m_) >> SHIFT;                     \
            atomicAdd(&lcnt[b_], 1u);                                           \
            atomicAdd(&lsum[b_], m_);                                           \
        }                                                                       \
    }

    // 4 float4 rounds (4096 elems) with register double-buffer
    {
        size_t idx = base + (size_t)t * 4;
        float4 yv = *reinterpret_cast<const float4*>(y + idx);
        float4 ov = *reinterpret_cast<const float4*>(o + idx);
        float4 wv = *reinterpret_cast<const float4*>(w + idx);
#pragma unroll
        for (int r = 0; r < 4; ++r) {
            float4 yn, on, wn;
            if (r + 1 < 4) {
                const size_t nidx = base + (size_t)((r + 1) * TPB + t) * 4;
                yn = *reinterpret_cast<const float4*>(y + nidx);
                on = *reinterpret_cast<const float4*>(o + nidx);
                wn = *reinterpret_cast<const float4*>(w + nidx);
            }
            PROC(yv.x, ov.x, wv.x) PROC(yv.y, ov.y, wv.y)
            PROC(yv.z, ov.z, wv.z) PROC(yv.w, ov.w, wv.w)
            if (r + 1 < 4) { yv = yn; ov = on; wv = wn; }
        }
    }
    // float2 tail (512 elems): offsets [4096, 4608)
    {
        const size_t idx = base + 4096 + (size_t)t * 2;
        const float2 yv = *reinterpret_cast<const float2*>(y + idx);
        const float2 ov = *reinterpret_cast<const float2*>(o + idx);
        const float2 wv = *reinterpret_cast<const float2*>(w + idx);
        PROC(yv.x, ov.x, wv.x) PROC(yv.y, ov.y, wv.y)
    }
#undef PROC

    // wave-level reduce of pos / mse -> LDS -> single plain store per block
#pragma unroll
    for (int off = 32; off > 0; off >>= 1) {
        msed += __shfl_down(msed, off);
        posd += __shfl_down(posd, off);
    }
    if ((t & 63) == 0) {
        const int wid = t >> 6;
        red[wid] = msed;
        red[(TPB / 64) + wid] = posd;
    }
    __syncthreads();

    // flush LDS histogram to this chunk's global slot (plain stores, coalesced)
    unsigned int* hc = hcnt_part + (size_t)g * NBINS;
    float* hs = hsum_part + (size_t)g * NBINS;
    for (int i = t; i < NBINS; i += TPB) {
        hc[i] = lcnt[i];
        hs[i] = lsum[i];
    }
    if (t == 0) {
        double m = 0.0, p = 0.0;
#pragma unroll
        for (int i = 0; i < TPB / 64; ++i) { m += red[i]; p += red[(TPB / 64) + i]; }
        mse_part[g] = m;
        pos_part[g] = p;
    }
}

// ---------------------------------------------------------------------------
// Kernel 2: reduce chunk histograms (phase 1, 1024 threads) then per-sample
// threshold selection (phase 2, first 256 threads) -> per-sample loss
// ---------------------------------------------------------------------------
__global__ __launch_bounds__(1024) void k_select(const unsigned int* __restrict__ hcnt_part,
                                                 const float* __restrict__ hsum_part,
                                                 const double* __restrict__ pos_part,
                                                 const float* __restrict__ tsv,
                                                 double* __restrict__ per_sample) {
    const int s = blockIdx.x;
    const int t = threadIdx.x;
    constexpr int BPT = NBINS / 256;  // 8 bins per select-thread

    __shared__ unsigned int fcnt[NBINS];
    __shared__ float fsum[NBINS];
    __shared__ unsigned int scnt[256], sufc[256];
    __shared__ double ssum[256], sufs[256];
    __shared__ unsigned int total_c;
    __shared__ double total_s;
    __shared__ double spos;

    // phase 0: sum this sample's 64 per-chunk pos partials (wave 0)
    if (t < 64) {
        double p = pos_part[s * CHUNKS + t];
#pragma unroll
        for (int off = 32; off > 0; off >>= 1) p += __shfl_down(p, off);
        if (t == 0) spos = p;
    }

    // phase 1: reduce 64 chunk histograms into LDS (2 bins per thread)
    for (int b = t; b < NBINS; b += 1024) {
        const unsigned int* cp = hcnt_part + ((size_t)s * CHUNKS) * NBINS + b;
        const float* sp = hsum_part + ((size_t)s * CHUNKS) * NBINS + b;
        unsigned int cacc = 0;
        float sacc = 0.0f;
#pragma unroll 4
        for (int c2 = 0; c2 < CHUNKS; ++c2) {
            cacc += cp[(size_t)c2 * NBINS];
            sacc += sp[(size_t)c2 * NBINS];
        }
        fcnt[b] = cacc;
        fsum[b] = sacc;
    }
    __syncthreads();

    // phase 2: select (first 256 threads), logic identical to proven R1/R2 code
    if (t < 256) {
        const int lo = t * BPT;
        unsigned int c = 0; double v = 0.0;
        for (int i = 0; i < BPT; ++i) { c += fcnt[lo + i]; v += (double)fsum[lo + i]; }
        scnt[t] = c; ssum[t] = v;
    }
    __syncthreads();
    if (t == 0) {
        unsigned int rc = 0; double rs = 0.0;
        for (int i = 255; i >= 0; --i) { sufc[i] = rc; sufs[i] = rs; rc += scnt[i]; rs += ssum[i]; }
        total_c = rc; total_s = rs;
    }
    __syncthreads();

    const float ts = tsv[s];
    if (t < 256) {
        long long kk = (long long)floorf(ts) * NEG_POS_RATIO;
        if (kk > N_) kk = N_;
        const int k = (int)kk;
        const int lo = t * BPT;

        double neg_loss = 0.0;
        bool have = false;

        if (k <= 0) {
            if (t == 0) { neg_loss = 0.0; have = true; }
        } else if ((unsigned int)k >= total_c) {
            if (t == 0) { neg_loss = total_s; have = true; }
        } else {
            const unsigned int S = sufc[t];
            if (S < (unsigned int)k && (unsigned int)k <= S + scnt[t]) {
                unsigned int c2 = S;
                double acc = sufs[t];
                for (int i = BPT - 1; i >= 0; --i) {
                    const unsigned int cb = fcnt[lo + i];
                    if (c2 + cb < (unsigned int)k) {
                        c2 += cb;
                        acc += (double)fsum[lo + i];
                    } else {
                        const unsigned int r = (unsigned int)k - c2;  // 1..cb
                        const float sb = fsum[lo + i];
                        if (r >= cb) {
                            acc += (double)sb;
                        } else {
                            // uniform-within-bin model
                            const float flo = __uint_as_float((unsigned int)(lo + i) << SHIFT);
                            const float fhi = __uint_as_float((unsigned int)(lo + i + 1) << SHIFT);
                            const double wd = (double)fhi - (double)flo;
                            const double mean = (double)sb / (double)cb;
                            double part = (double)r * (mean + wd * (double)(cb - r) / (2.0 * (double)cb));
                            const double cap = (double)r * (double)fhi;
                            if (part > (double)sb) part = (double)sb;
                            if (part > cap) part = cap;
                            if (part < 0.0) part = 0.0;
                            acc += part;
                        }
                        break;
                    }
                }
                neg_loss = acc;
                have = true;
            }
        }

        if (have) {
            const double p = spos;
            const double safe = (ts > 0.0f) ? (double)ts : 1.0;
            const double psamp = (p + neg_loss) / safe;  // ALPHA = 1.0
            per_sample[s] = (ts > 0.0f) ? psamp : 0.0;
        }
    }
}

// ---------------------------------------------------------------------------
// Kernel 3: combine per-sample losses + mse partials -> scalar output
// ---------------------------------------------------------------------------
__global__ __launch_bounds__(256) void k_final(const double* __restrict__ per_sample,
                                               const double* __restrict__ mse_part,
                                               float* __restrict__ out) {
    const int t = threadIdx.x;
    __shared__ double sm[4], sv[4];
    double m = 0.0;
    for (int i = t; i < NCHUNKS_TOTAL; i += 256) m += mse_part[i];
    double v = (t < B_) ? per_sample[t] : 0.0;
#pragma unroll
    for (int off = 32; off > 0; off >>= 1) {
        m += __shfl_down(m, off);
        v += __shfl_down(v, off);
    }
    if ((t & 63) == 0) { sm[t >> 6] = m; sv[t >> 6] = v; }
    __syncthreads();
    if (t == 0) {
        double mt = 0.0, vt = 0.0;
#pragma unroll
        for (int i = 0; i < 4; ++i) { mt += sm[i]; vt += sv[i]; }
        const double train = vt / (double)B_;
        const double mean = mt / ((double)B_ * (double)N_);
        out[0] = (float)((train + mean) * 10.0);
    }
}

// ---------------------------------------------------------------------------
extern "C" void kernel_launch(void* const* d_in, const int* in_sizes, int n_in,
                              void* d_out, int out_size, void* d_ws, size_t ws_size,
                              hipStream_t stream) {
    const float* y = (const float*)d_in[0];
    const float* o = (const float*)d_in[1];
    const float* w = (const float*)d_in[2];
    const float* ts = (const float*)d_in[3];

    unsigned char* ws = (unsigned char*)d_ws;
    // chunk histograms: 2048 chunks x 2048 bins
    unsigned int* hcnt_part = (unsigned int*)ws;                                   // 16 MB
    float* hsum_part = (float*)(ws + (size_t)NCHUNKS_TOTAL * NBINS * 4);           // 16 MB
    double* pos_part = (double*)(ws + (size_t)NCHUNKS_TOTAL * NBINS * 8);          // 16 KB
    double* mse_part = pos_part + NCHUNKS_TOTAL;                                   // 16 KB
    double* per_sample = mse_part + NCHUNKS_TOTAL;                                 // 256 B

    // NO zero-init required: all workspace locations are written unconditionally
    // by plain stores before being read.

    dim3 g1(CHUNKS, B_);
    hipLaunchKernelGGL(k_hist, g1, dim3(TPB), 0, stream, y, o, w,
                       hcnt_part, hsum_part, pos_part, mse_part);
    hipLaunchKernelGGL(k_select, dim3(B_), dim3(1024), 0, stream,
                       hcnt_part, hsum_part, pos_part, ts, per_sample);
    hipLaunchKernelGGL(k_final, dim3(1), dim3(256), 0, stream,
                       per_sample, mse_part, (float*)d_out);
}

// Round 4
// 45.537 us; speedup vs baseline: 1.3869x; 1.3869x over previous
//
#include <hip/hip_runtime.h>

// Problem constants (from reference): B=32, H=384, W=384, C=2
static constexpr int B_ = 32;
static constexpr int N_ = 384 * 384 * 2;          // 294912 elements per sample
static constexpr int CHUNKS = 64;                 // blocks per sample
static constexpr int EPB = N_ / CHUNKS;           // 4608 elements per block
static constexpr int TPB = 256;                   // 4 waves
static constexpr int NBINS = 2048;                // float bits >> 20: 8 exp + 3 mantissa
static constexpr int SHIFT = 20;
static constexpr int NEG_POS_RATIO = 3;
static constexpr int NCHUNKS_TOTAL = B_ * CHUNKS; // 2048
static constexpr float FSCALE = 4194304.0f;       // 2^22 fixed-point scale
static constexpr double INV_FSCALE = 1.0 / 4194304.0;
static constexpr unsigned long long M40 = (1ULL << 40) - 1;

// ---------------------------------------------------------------------------
// Kernel 0: zero the merged per-sample histogram (32 x 2048 x u64 = 512 KB)
// ---------------------------------------------------------------------------
__global__ __launch_bounds__(256) void k_zero(unsigned long long* __restrict__ hist) {
    const int i = blockIdx.x * 256 + threadIdx.x;   // 128 blocks x 256 = 32768
    reinterpret_cast<ulonglong2*>(hist)[i] = ulonglong2{0ull, 0ull};
}

// ---------------------------------------------------------------------------
// Kernel 1: stream y/o/w; ONE packed u64 LDS atomic per neg element
// (count in bits 40+, fixed-point value sum in bits 0..39); f32 pos/mse
// accumulators; merge non-empty bins into per-sample global hist (u64 atomic).
// ---------------------------------------------------------------------------
__global__ __launch_bounds__(TPB, 8) void k_hist(const float* __restrict__ y,
                                                 const float* __restrict__ o,
                                                 const float* __restrict__ w,
                                                 unsigned long long* __restrict__ hist,
                                                 double* __restrict__ pos_part,
                                                 double* __restrict__ mse_part) {
    __shared__ unsigned long long lhist[NBINS];   // 16 KB
    __shared__ float redm[TPB / 64], redp[TPB / 64];
    const int s = blockIdx.y;
    const int c = blockIdx.x;
    const int g = s * CHUNKS + c;
    const int t = threadIdx.x;
    for (int i = t; i < NBINS; i += TPB) lhist[i] = 0ull;
    __syncthreads();

    const size_t base = (size_t)s * N_ + (size_t)c * EPB;
    float msef = 0.0f, posf = 0.0f;

#define PROC(yy, oo, ww)                                                        \
    {                                                                           \
        const float d_ = (oo) - (yy);                                           \
        const float m_ = d_ * d_;                                               \
        msef += m_;                                                             \
        if ((ww) > 0.0f) {                                                      \
            posf += (ww) * m_;                                                  \
        } else if ((oo) > 0.0f) {                                               \
            const unsigned int b_ = __float_as_uint(m_) >> SHIFT;               \
            const unsigned long long pk =                                       \
                (1ULL << 40) | (unsigned long long)(unsigned int)(m_ * FSCALE); \
            atomicAdd(&lhist[b_], pk);                                          \
        }                                                                       \
    }
#define PROC4(V)  PROC(Y##V.x, O##V.x, W##V.x) PROC(Y##V.y, O##V.y, W##V.y) \
                  PROC(Y##V.z, O##V.z, W##V.z) PROC(Y##V.w, O##V.w, W##V.w)
#define LD4(arr, r) (*reinterpret_cast<const float4*>((arr) + base + (size_t)((r) * TPB + t) * 4))

    // depth-2 register pipeline over 4 float4 rounds (4096 elems) + f2 tail (512)
    float4 Ya = LD4(y, 0), Oa = LD4(o, 0), Wa = LD4(w, 0);
    float4 Yb = LD4(y, 1), Ob = LD4(o, 1), Wb = LD4(w, 1);
    {
        const float4 Yn = LD4(y, 2), On = LD4(o, 2), Wn = LD4(w, 2);
        PROC4(a)
        Ya = Yn; Oa = On; Wa = Wn;
    }
    {
        const float4 Yn = LD4(y, 3), On = LD4(o, 3), Wn = LD4(w, 3);
        PROC4(b)
        Yb = Yn; Ob = On; Wb = Wn;
    }
    {
        const size_t tix = base + 4096 + (size_t)t * 2;
        const float2 yt = *reinterpret_cast<const float2*>(y + tix);
        const float2 ot = *reinterpret_cast<const float2*>(o + tix);
        const float2 wt = *reinterpret_cast<const float2*>(w + tix);
        PROC4(a)
        PROC4(b)
        PROC(yt.x, ot.x, wt.x) PROC(yt.y, ot.y, wt.y)
    }
#undef LD4
#undef PROC4
#undef PROC

    // wave reduce (f32), one LDS slot per wave
#pragma unroll
    for (int off = 32; off > 0; off >>= 1) {
        msef += __shfl_down(msef, off);
        posf += __shfl_down(posf, off);
    }
    if ((t & 63) == 0) { redm[t >> 6] = msef; redp[t >> 6] = posf; }
    __syncthreads();

    // merge non-empty bins into the per-sample global histogram
    unsigned long long* hs = hist + (size_t)s * NBINS;
    for (int i = t; i < NBINS; i += TPB) {
        const unsigned long long v = lhist[i];
        if (v) atomicAdd(&hs[i], v);
    }
    if (t == 0) {
        double m = 0.0, p = 0.0;
#pragma unroll
        for (int i = 0; i < TPB / 64; ++i) { m += (double)redm[i]; p += (double)redp[i]; }
        mse_part[g] = m;
        pos_part[g] = p;
    }
}

// ---------------------------------------------------------------------------
// Kernel 2: per-sample threshold selection from merged histogram
// ---------------------------------------------------------------------------
__global__ __launch_bounds__(256) void k_select(const unsigned long long* __restrict__ hist,
                                                const double* __restrict__ pos_part,
                                                const float* __restrict__ tsv,
                                                double* __restrict__ per_sample) {
    const int s = blockIdx.x;
    const int t = threadIdx.x;
    constexpr int BPT = NBINS / 256;  // 8 bins per thread

    __shared__ unsigned int scnt[256], sufc[256];
    __shared__ double ssum[256], sufs[256];
    __shared__ unsigned int total_c;
    __shared__ double total_s;
    __shared__ double spos;

    // sum this sample's 64 per-chunk pos partials (wave 0)
    if (t < 64) {
        double p = pos_part[s * CHUNKS + t];
#pragma unroll
        for (int off = 32; off > 0; off >>= 1) p += __shfl_down(p, off);
        if (t == 0) spos = p;
    }

    const int lo = t * BPT;
    unsigned long long bb[BPT];
#pragma unroll
    for (int i = 0; i < BPT; ++i) bb[i] = hist[(size_t)s * NBINS + lo + i];

    unsigned int c = 0; double v = 0.0;
#pragma unroll
    for (int i = 0; i < BPT; ++i) {
        c += (unsigned int)(bb[i] >> 40);
        v += (double)(bb[i] & M40) * INV_FSCALE;
    }
    scnt[t] = c; ssum[t] = v;
    __syncthreads();
    if (t == 0) {
        unsigned int rc = 0; double rs = 0.0;
        for (int i = 255; i >= 0; --i) { sufc[i] = rc; sufs[i] = rs; rc += scnt[i]; rs += ssum[i]; }
        total_c = rc; total_s = rs;
    }
    __syncthreads();

    const float ts = tsv[s];
    long long kk = (long long)floorf(ts) * NEG_POS_RATIO;
    if (kk > N_) kk = N_;
    const int k = (int)kk;

    double neg_loss = 0.0;
    bool have = false;

    if (k <= 0) {
        if (t == 0) { neg_loss = 0.0; have = true; }
    } else if ((unsigned int)k >= total_c) {
        if (t == 0) { neg_loss = total_s; have = true; }
    } else {
        const unsigned int S = sufc[t];
        if (S < (unsigned int)k && (unsigned int)k <= S + scnt[t]) {
            unsigned int c2 = S;
            double acc = sufs[t];
            bool done = false;
#pragma unroll
            for (int i = BPT - 1; i >= 0; --i) {
                if (!done) {
                    const unsigned int cb = (unsigned int)(bb[i] >> 40);
                    const double sb = (double)(bb[i] & M40) * INV_FSCALE;
                    if (c2 + cb < (unsigned int)k) {
                        c2 += cb;
                        acc += sb;
                    } else {
                        const unsigned int r = (unsigned int)k - c2;  // 1..cb
                        if (r >= cb) {
                            acc += sb;
                        } else {
                            // uniform-within-bin model: top-r sum
                            const float flo = __uint_as_float((unsigned int)(lo + i) << SHIFT);
                            const float fhi = __uint_as_float((unsigned int)(lo + i + 1) << SHIFT);
                            const double wd = (double)fhi - (double)flo;
                            const double mean = sb / (double)cb;
                            double part = (double)r * (mean + wd * (double)(cb - r) / (2.0 * (double)cb));
                            const double cap = (double)r * (double)fhi;
                            if (part > sb) part = sb;
                            if (part > cap) part = cap;
                            if (part < 0.0) part = 0.0;
                            acc += part;
                        }
                        done = true;
                    }
                }
            }
            neg_loss = acc;
            have = true;
        }
    }

    if (have) {
        const double safe = (ts > 0.0f) ? (double)ts : 1.0;
        const double psamp = (spos + neg_loss) / safe;  // ALPHA = 1.0
        per_sample[s] = (ts > 0.0f) ? psamp : 0.0;
    }
}

// ---------------------------------------------------------------------------
// Kernel 3: combine per-sample losses + mse partials -> scalar output
// ---------------------------------------------------------------------------
__global__ __launch_bounds__(256) void k_final(const double* __restrict__ per_sample,
                                               const double* __restrict__ mse_part,
                                               float* __restrict__ out) {
    const int t = threadIdx.x;
    __shared__ double sm[4], sv[4];
    double m = 0.0;
    for (int i = t; i < NCHUNKS_TOTAL; i += 256) m += mse_part[i];
    double v = (t < B_) ? per_sample[t] : 0.0;
#pragma unroll
    for (int off = 32; off > 0; off >>= 1) {
        m += __shfl_down(m, off);
        v += __shfl_down(v, off);
    }
    if ((t & 63) == 0) { sm[t >> 6] = m; sv[t >> 6] = v; }
    __syncthreads();
    if (t == 0) {
        double mt = 0.0, vt = 0.0;
#pragma unroll
        for (int i = 0; i < 4; ++i) { mt += sm[i]; vt += sv[i]; }
        const double train = vt / (double)B_;
        const double mean = mt / ((double)B_ * (double)N_);
        out[0] = (float)((train + mean) * 10.0);
    }
}

// ---------------------------------------------------------------------------
extern "C" void kernel_launch(void* const* d_in, const int* in_sizes, int n_in,
                              void* d_out, int out_size, void* d_ws, size_t ws_size,
                              hipStream_t stream) {
    const float* y = (const float*)d_in[0];
    const float* o = (const float*)d_in[1];
    const float* w = (const float*)d_in[2];
    const float* ts = (const float*)d_in[3];

    unsigned char* ws = (unsigned char*)d_ws;
    unsigned long long* hist = (unsigned long long*)ws;                 // 32*2048*8 = 512 KB
    double* pos_part = (double*)(ws + (size_t)B_ * NBINS * 8);          // 2048 doubles
    double* mse_part = pos_part + NCHUNKS_TOTAL;                        // 2048 doubles
    double* per_sample = mse_part + NCHUNKS_TOTAL;                      // 32 doubles

    hipLaunchKernelGGL(k_zero, dim3(128), dim3(256), 0, stream, hist);
    dim3 g1(CHUNKS, B_);
    hipLaunchKernelGGL(k_hist, g1, dim3(TPB), 0, stream, y, o, w, hist, pos_part, mse_part);
    hipLaunchKernelGGL(k_select, dim3(B_), dim3(256), 0, stream, hist, pos_part, ts, per_sample);
    hipLaunchKernelGGL(k_final, dim3(1), dim3(256), 0, stream, per_sample, mse_part, (float*)d_out);
}

// Round 5
// 42.016 us; speedup vs baseline: 1.5031x; 1.0838x over previous
//
#include <hip/hip_runtime.h>

// Problem constants (from reference): B=32, H=384, W=384, C=2
static constexpr int B_ = 32;
static constexpr int N_ = 384 * 384 * 2;          // 294912 elements per sample
static constexpr int CHUNKS = 64;                 // blocks per sample
static constexpr int EPB = N_ / CHUNKS;           // 4608 elements per block
static constexpr int TPB = 256;                   // 4 waves
static constexpr int NBINS = 1024;                // float bits >> 21: 8 exp + 2 mantissa
static constexpr int SHIFT = 21;
static constexpr int NEG_POS_RATIO = 3;
static constexpr int NCHUNKS_TOTAL = B_ * CHUNKS; // 2048
// LDS u32 pack: count in bits 22..31 (max 1023), sum*64 in bits 0..21
static constexpr float FSCALE = 64.0f;
static constexpr double INV_FSCALE = 1.0 / 64.0;
static constexpr unsigned long long M40 = (1ULL << 40) - 1;

// ---------------------------------------------------------------------------
// Kernel 0: zero the merged per-sample histogram (32 x 1024 x u64 = 256 KB)
// and the completion counter.
// ---------------------------------------------------------------------------
__global__ __launch_bounds__(256) void k_zero(unsigned long long* __restrict__ hist,
                                              unsigned int* __restrict__ counter) {
    const int i = blockIdx.x * 256 + threadIdx.x;   // 64 blocks x 256 = 16384 x 16B
    reinterpret_cast<ulonglong2*>(hist)[i] = ulonglong2{0ull, 0ull};
    if (i == 0) *counter = 0u;
}

// ---------------------------------------------------------------------------
// Kernel 1: stream y/o/w; ONE packed u32 LDS atomic per neg element;
// f32 pos/mse accumulators; merge non-empty bins into per-sample global
// u64 hist (count<<40 | sum-units).
// ---------------------------------------------------------------------------
__global__ __launch_bounds__(TPB, 8) void k_hist(const float* __restrict__ y,
                                                 const float* __restrict__ o,
                                                 const float* __restrict__ w,
                                                 unsigned long long* __restrict__ hist,
                                                 double* __restrict__ pos_part,
                                                 double* __restrict__ mse_part) {
    __shared__ unsigned int lhist[NBINS];         // 4 KB
    __shared__ float redm[TPB / 64], redp[TPB / 64];
    const int s = blockIdx.y;
    const int c = blockIdx.x;
    const int g = s * CHUNKS + c;
    const int t = threadIdx.x;
    for (int i = t; i < NBINS; i += TPB) lhist[i] = 0u;
    __syncthreads();

    const size_t base = (size_t)s * N_ + (size_t)c * EPB;
    float msef = 0.0f, posf = 0.0f;

#define PROC(yy, oo, ww)                                                        \
    {                                                                           \
        const float d_ = (oo) - (yy);                                           \
        const float m_ = d_ * d_;                                               \
        msef += m_;                                                             \
        if ((ww) > 0.0f) {                                                      \
            posf += (ww) * m_;                                                  \
        } else if ((oo) > 0.0f) {                                               \
            const unsigned int b_ = __float_as_uint(m_) >> SHIFT;               \
            const unsigned int pk = (1u << 22) | (unsigned int)(m_ * FSCALE);   \
            atomicAdd(&lhist[b_], pk);                                          \
        }                                                                       \
    }
#define PROC4(V)  PROC(Y##V.x, O##V.x, W##V.x) PROC(Y##V.y, O##V.y, W##V.y) \
                  PROC(Y##V.z, O##V.z, W##V.z) PROC(Y##V.w, O##V.w, W##V.w)
#define LD4(arr, r) (*reinterpret_cast<const float4*>((arr) + base + (size_t)((r) * TPB + t) * 4))

    // depth-2 register pipeline over 4 float4 rounds (4096 elems) + f2 tail (512)
    float4 Ya = LD4(y, 0), Oa = LD4(o, 0), Wa = LD4(w, 0);
    float4 Yb = LD4(y, 1), Ob = LD4(o, 1), Wb = LD4(w, 1);
    {
        const float4 Yn = LD4(y, 2), On = LD4(o, 2), Wn = LD4(w, 2);
        PROC4(a)
        Ya = Yn; Oa = On; Wa = Wn;
    }
    {
        const float4 Yn = LD4(y, 3), On = LD4(o, 3), Wn = LD4(w, 3);
        PROC4(b)
        Yb = Yn; Ob = On; Wb = Wn;
    }
    {
        const size_t tix = base + 4096 + (size_t)t * 2;
        const float2 yt = *reinterpret_cast<const float2*>(y + tix);
        const float2 ot = *reinterpret_cast<const float2*>(o + tix);
        const float2 wt = *reinterpret_cast<const float2*>(w + tix);
        PROC4(a)
        PROC4(b)
        PROC(yt.x, ot.x, wt.x) PROC(yt.y, ot.y, wt.y)
    }
#undef LD4
#undef PROC4
#undef PROC

    // wave reduce (f32), one LDS slot per wave
#pragma unroll
    for (int off = 32; off > 0; off >>= 1) {
        msef += __shfl_down(msef, off);
        posf += __shfl_down(posf, off);
    }
    if ((t & 63) == 0) { redm[t >> 6] = msef; redp[t >> 6] = posf; }
    __syncthreads();

    // merge non-empty bins into the per-sample global histogram (u64)
    unsigned long long* hs = hist + (size_t)s * NBINS;
    for (int i = t; i < NBINS; i += TPB) {
        const unsigned int v = lhist[i];
        if (v) {
            const unsigned long long pk =
                ((unsigned long long)(v >> 22) << 40) | (unsigned long long)(v & 0x3FFFFFu);
            atomicAdd(&hs[i], pk);
        }
    }
    if (t == 0) {
        double m = 0.0, p = 0.0;
#pragma unroll
        for (int i = 0; i < TPB / 64; ++i) { m += (double)redm[i]; p += (double)redp[i]; }
        mse_part[g] = m;
        pos_part[g] = p;
    }
}

// ---------------------------------------------------------------------------
// Kernel 2: per-sample threshold selection + (last block) final combine
// ---------------------------------------------------------------------------
__global__ __launch_bounds__(256) void k_select(const unsigned long long* __restrict__ hist,
                                                const double* __restrict__ pos_part,
                                                const double* __restrict__ mse_part,
                                                const float* __restrict__ tsv,
                                                double* __restrict__ per_sample,
                                                unsigned int* __restrict__ counter,
                                                float* __restrict__ out) {
    const int s = blockIdx.x;
    const int t = threadIdx.x;
    constexpr int BPT = NBINS / 256;  // 4 bins per thread

    __shared__ unsigned int scnt[256], sufc[256];
    __shared__ double ssum[256], sufs[256];
    __shared__ unsigned int total_c;
    __shared__ double total_s;
    __shared__ double spos;
    __shared__ int is_last;

    // sum this sample's 64 per-chunk pos partials (wave 0)
    if (t < 64) {
        double p = pos_part[s * CHUNKS + t];
#pragma unroll
        for (int off = 32; off > 0; off >>= 1) p += __shfl_down(p, off);
        if (t == 0) spos = p;
    }

    const int lo = t * BPT;
    unsigned long long bb[BPT];
#pragma unroll
    for (int i = 0; i < BPT; ++i) bb[i] = hist[(size_t)s * NBINS + lo + i];

    unsigned int c = 0; double v = 0.0;
#pragma unroll
    for (int i = 0; i < BPT; ++i) {
        c += (unsigned int)(bb[i] >> 40);
        v += (double)(bb[i] & M40) * INV_FSCALE;
    }
    scnt[t] = c; ssum[t] = v;
    __syncthreads();
    if (t == 0) {
        unsigned int rc = 0; double rs = 0.0;
        for (int i = 255; i >= 0; --i) { sufc[i] = rc; sufs[i] = rs; rc += scnt[i]; rs += ssum[i]; }
        total_c = rc; total_s = rs;
    }
    __syncthreads();

    const float ts = tsv[s];
    long long kk = (long long)floorf(ts) * NEG_POS_RATIO;
    if (kk > N_) kk = N_;
    const int k = (int)kk;

    double neg_loss = 0.0;
    bool have = false;

    if (k <= 0) {
        if (t == 0) { neg_loss = 0.0; have = true; }
    } else if ((unsigned int)k >= total_c) {
        if (t == 0) { neg_loss = total_s; have = true; }
    } else {
        const unsigned int S = sufc[t];
        if (S < (unsigned int)k && (unsigned int)k <= S + scnt[t]) {
            unsigned int c2 = S;
            double acc = sufs[t];
            bool done = false;
#pragma unroll
            for (int i = BPT - 1; i >= 0; --i) {
                if (!done) {
                    const unsigned int cb = (unsigned int)(bb[i] >> 40);
                    const double sb = (double)(bb[i] & M40) * INV_FSCALE;
                    if (c2 + cb < (unsigned int)k) {
                        c2 += cb;
                        acc += sb;
                    } else {
                        const unsigned int r = (unsigned int)k - c2;  // 1..cb
                        if (r >= cb) {
                            acc += sb;
                        } else {
                            // uniform-within-bin model: top-r sum
                            const float flo = __uint_as_float((unsigned int)(lo + i) << SHIFT);
                            const float fhi = __uint_as_float((unsigned int)(lo + i + 1) << SHIFT);
                            const double wd = (double)fhi - (double)flo;
                            const double mean = sb / (double)cb;
                            double part = (double)r * (mean + wd * (double)(cb - r) / (2.0 * (double)cb));
                            const double cap = (double)r * (double)fhi;
                            if (part > sb) part = sb;
                            if (part > cap) part = cap;
                            if (part < 0.0) part = 0.0;
                            acc += part;
                        }
                        done = true;
                    }
                }
            }
            neg_loss = acc;
            have = true;
        }
    }

    if (have) {
        const double safe = (ts > 0.0f) ? (double)ts : 1.0;
        const double psamp = (spos + neg_loss) / safe;  // ALPHA = 1.0
        per_sample[s] = (ts > 0.0f) ? psamp : 0.0;
    }
    __syncthreads();

    // completion ticket: last block computes the final scalar
    if (t == 0) {
        __threadfence();
        const unsigned int old = atomicAdd(counter, 1u);
        is_last = (old == (unsigned int)(B_ - 1)) ? 1 : 0;
    }
    __syncthreads();
    if (is_last) {
        __threadfence();
        __shared__ double sm[4], sv[4];
        double m = 0.0;
        for (int i = t; i < NCHUNKS_TOTAL; i += 256) m += mse_part[i];
        double vv = 0.0;
        if (t < B_) vv = ((volatile double*)per_sample)[t];
#pragma unroll
        for (int off = 32; off > 0; off >>= 1) {
            m += __shfl_down(m, off);
            vv += __shfl_down(vv, off);
        }
        if ((t & 63) == 0) { sm[t >> 6] = m; sv[t >> 6] = vv; }
        __syncthreads();
        if (t == 0) {
            double mt = 0.0, vt = 0.0;
#pragma unroll
            for (int i = 0; i < 4; ++i) { mt += sm[i]; vt += sv[i]; }
            const double train = vt / (double)B_;
            const double mean = mt / ((double)B_ * (double)N_);
            out[0] = (float)((train + mean) * 10.0);
        }
    }
}

// ---------------------------------------------------------------------------
extern "C" void kernel_launch(void* const* d_in, const int* in_sizes, int n_in,
                              void* d_out, int out_size, void* d_ws, size_t ws_size,
                              hipStream_t stream) {
    const float* y = (const float*)d_in[0];
    const float* o = (const float*)d_in[1];
    const float* w = (const float*)d_in[2];
    const float* ts = (const float*)d_in[3];

    unsigned char* ws = (unsigned char*)d_ws;
    unsigned long long* hist = (unsigned long long*)ws;                 // 32*1024*8 = 256 KB
    double* pos_part = (double*)(ws + (size_t)B_ * NBINS * 8);          // 2048 doubles
    double* mse_part = pos_part + NCHUNKS_TOTAL;                        // 2048 doubles
    double* per_sample = mse_part + NCHUNKS_TOTAL;                      // 32 doubles
    unsigned int* counter = (unsigned int*)(per_sample + B_);           // 1 u32

    hipLaunchKernelGGL(k_zero, dim3(64), dim3(256), 0, stream, hist, counter);
    dim3 g1(CHUNKS, B_);
    hipLaunchKernelGGL(k_hist, g1, dim3(TPB), 0, stream, y, o, w, hist, pos_part, mse_part);
    hipLaunchKernelGGL(k_select, dim3(B_), dim3(256), 0, stream,
                       hist, pos_part, mse_part, ts, per_sample, counter, (float*)d_out);
}